// Round 11
// baseline (415.153 us; speedup 1.0000x reference)
//
#include <hip/hip_runtime.h>

#define B_DIM 128
#define T_DIM 512
#define C_DIM 384
#define NH_DIM 6
#define HD_DIM 64
#define QKV_LD 1152  // 3*C

typedef __bf16 bf16x8 __attribute__((ext_vector_type(8)));
typedef __bf16 bf16x4 __attribute__((ext_vector_type(4)));
typedef float f32x4 __attribute__((ext_vector_type(4)));

// (1/sqrt(64)) * log2(e): folded into Q inside gemm1's epilogue, so attention
// scores come out of QK^T already in the exp2 domain.
#define K_SCALE 0.18033688011112042f

// direct global->LDS DMA, 16B per lane. LDS dest is wave-uniform base +
// lane*16 (m104); the global source is per-lane, which is how the k-slot
// swizzle is applied (m173 pattern).
__device__ __forceinline__ void gload_lds16(const __bf16* g, __bf16* l) {
  __builtin_amdgcn_global_load_lds(
      (const __attribute__((address_space(1))) void*)g,
      (__attribute__((address_space(3))) void*)l, 16, 0, 0);
}

// ---------------- fp32 -> bf16 cast for the two weight matrices ------------
// x's cast is now fused into gemm1's A-staging; only Wqkv+Wout remain
// (147456 float4 units = exactly 576 blocks).
#define WQKV_F4 110592
#define WOUT_F4 36864
__global__ __launch_bounds__(256) void cast_w(const float* __restrict__ wqkv,
                                              const float* __restrict__ wout,
                                              __bf16* __restrict__ wqkvb,
                                              __bf16* __restrict__ woutb) {
  int i = blockIdx.x * blockDim.x + threadIdx.x;
  const float4* src;
  bf16x4* dst;
  if (i < WQKV_F4) {
    src = (const float4*)wqkv + i;
    dst = (bf16x4*)wqkvb + i;
  } else {
    src = (const float4*)wout + (i - WQKV_F4);
    dst = (bf16x4*)woutb + (i - WQKV_F4);
  }
  float4 v = *src;
  bf16x4 o;
  o[0] = (__bf16)v.x; o[1] = (__bf16)v.y; o[2] = (__bf16)v.z; o[3] = (__bf16)v.w;
  *dst = o;
}

// ---------------- C = A * B^T  (+ fused RoPE, Q pre-scale, fp32-A cast) ----
// A[M][K] row-major: bf16 (A, DMA-staged) OR fp32 (Af, reg-staged with fused
// cast -- deletes the standalone x-cast pass). B[N][K] bf16. C -> bf16 Cb or
// fp32 Cf.
// T1 XCD SWIZZLE: consecutive dispatch ids round-robin across the 8 XCD L2s,
// so the 9 consecutive blocks sharing an A-panel each re-fetched it (R10:
// FETCH 216 MB vs ~51 ideal). Remap swz = (bid&7)*(nwg/8) + bid>>3 -> each
// XCD gets a CONTIGUOUS chunk of the n-fastest logical order; panel fetched
// once per XCD L2. nwg must be %8==0 (4608, 1536 both are).
// R10's counted-vmcnt pipeline measured null -> reverted to the plain
// 2-barrier loop (also required: extra fp32 loads would break counted vmcnt).
// fp32-A staging is T14-split: tile k+1's float4 loads are issued right after
// the second barrier, so their latency hides under tile k's MFMA phase; only
// the cvt+ds_write sits between the barriers.
__global__ __launch_bounds__(256) void gemm_bt(const __bf16* __restrict__ A,
                                               const float* __restrict__ Af,
                                               const __bf16* __restrict__ Bm,
                                               __bf16* __restrict__ Cb,
                                               float* __restrict__ Cf,
                                               const float* __restrict__ cosp,
                                               const float* __restrict__ sinp,
                                               int M, int N, int K) {
  __shared__ __attribute__((aligned(16))) __bf16 As[128 * 32];  // 8 KB
  __shared__ __attribute__((aligned(16))) __bf16 Bs[128 * 32];  // 8 KB
  const int nwg = gridDim.x * gridDim.y;
  const int bid = blockIdx.x + gridDim.x * blockIdx.y;  // dispatch order (x fastest)
  const int per = nwg >> 3;
  const int swz = (bid & 7) * per + (bid >> 3);         // T1, bijective (nwg%8==0)
  const int m0 = (swz / gridDim.x) * 128;
  const int n0 = (swz % gridDim.x) * 128;
  const int tid = threadIdx.x;
  const int wave = tid >> 6;
  const int lane = tid & 63;
  const int lr = lane & 15;
  const int quad = lane >> 4;
  const int wm = (wave & 1) * 64;
  const int wn = (wave >> 1) * 64;
  const int ca0 = wave * 2, ca1 = wave * 2 + 1;
  const int srow = lane >> 2;
  const int row0 = ca0 * 16 + srow, row1 = ca1 * 16 + srow;
  const int slot = (lane & 3) ^ ((lane >> 3) & 3);  // (l&3) ^ ((srow>>1)&3)
  const int rs = (quad ^ ((lr >> 1) & 3)) * 8;
  // fp32-A reg staging: lane covers the same 16B (8 elems) it would DMA.
  float4 ar[2][2];
  auto loadA = [&](int k0) {
#pragma unroll
    for (int c = 0; c < 2; ++c) {
      const int row = (wave * 2 + c) * 16 + srow;
      const float4* p = (const float4*)&Af[(size_t)(m0 + row) * K + k0 + slot * 8];
      ar[c][0] = p[0];
      ar[c][1] = p[1];
    }
  };
  if (Af) loadA(0);
  f32x4 acc[4][4] = {};
  for (int k0 = 0; k0 < K; k0 += 32) {
    __syncthreads();  // prev iteration's LDS reads done
    if (Af) {
#pragma unroll
      for (int c = 0; c < 2; ++c) {
        bf16x8 w;
        w[0] = (__bf16)ar[c][0].x; w[1] = (__bf16)ar[c][0].y;
        w[2] = (__bf16)ar[c][0].z; w[3] = (__bf16)ar[c][0].w;
        w[4] = (__bf16)ar[c][1].x; w[5] = (__bf16)ar[c][1].y;
        w[6] = (__bf16)ar[c][1].z; w[7] = (__bf16)ar[c][1].w;
        *(bf16x8*)&As[(wave * 2 + c) * 512 + lane * 8] = w;
      }
    } else {
      gload_lds16(&A[(size_t)(m0 + row0) * K + k0 + slot * 8], &As[ca0 * 512]);
      gload_lds16(&A[(size_t)(m0 + row1) * K + k0 + slot * 8], &As[ca1 * 512]);
    }
    gload_lds16(&Bm[(size_t)(n0 + row0) * K + k0 + slot * 8], &Bs[ca0 * 512]);
    gload_lds16(&Bm[(size_t)(n0 + row1) * K + k0 + slot * 8], &Bs[ca1 * 512]);
    __syncthreads();  // stage visible (compiler drains vm+lgkm)
    if (Af && k0 + 32 < K) loadA(k0 + 32);  // T14: fly under the MFMA phase
    bf16x8 af[4], bf[4];
#pragma unroll
    for (int i = 0; i < 4; ++i)
      af[i] = *(bf16x8*)&As[(wm + i * 16 + lr) * 32 + rs];
#pragma unroll
    for (int j = 0; j < 4; ++j)
      bf[j] = *(bf16x8*)&Bs[(wn + j * 16 + lr) * 32 + rs];
#pragma unroll
    for (int i = 0; i < 4; ++i)
#pragma unroll
      for (int j = 0; j < 4; ++j)
        acc[i][j] = __builtin_amdgcn_mfma_f32_16x16x32_bf16(af[i], bf[j], acc[i][j], 0, 0, 0);
  }
  // D layout: col = lane&15, row = quad*4 + r  (m89-verified)
  const bool doRope = (cosp != nullptr);
#pragma unroll
  for (int i = 0; i < 4; ++i) {
#pragma unroll
    for (int j = 0; j < 4; ++j) {
      int gm = m0 + wm + i * 16 + quad * 4;
      int gn = n0 + wn + j * 16 + lr;
      if (Cf) {
#pragma unroll
        for (int r = 0; r < 4; ++r) Cf[(size_t)(gm + r) * N + gn] = acc[i][j][r];
      } else {
        const int cbase = n0 + wn + j * 16;
        const bool ropeBlk = doRope && (cbase < 2 * C_DIM) && ((cbase & 63) == 0);
        const float qs = (doRope && cbase < C_DIM) ? K_SCALE : 1.0f;
        if (ropeBlk) {
#pragma unroll
          for (int r = 0; r < 4; ++r) {
            float v = acc[i][j][r];
            float p = __shfl_xor(v, 8, 64);  // partner dim (d <-> d+8), same quad
            int t = (gm + r) & (T_DIM - 1);
            float c = cosp[t * 8 + (lr & 7)];
            float s = sinp[t * 8 + (lr & 7)];
            v = (lr & 8) ? __builtin_fmaf(v, c, p * s)
                         : __builtin_fmaf(v, c, -p * s);
            Cb[(size_t)(gm + r) * N + gn] = (__bf16)(v * qs);
          }
        } else {
#pragma unroll
          for (int r = 0; r < 4; ++r)
            Cb[(size_t)(gm + r) * N + gn] = (__bf16)(acc[i][j][r] * qs);
        }
      }
    }
  }
}

// ---------------- V transpose: vt[b][h][d][t] <- qkv[b*T+t][768 + h*64 + d] ----------------
__global__ __launch_bounds__(256) void transpose_v(const __bf16* __restrict__ qkv,
                                                   __bf16* __restrict__ vt) {
  __shared__ __attribute__((aligned(16))) __bf16 Tl[64][72];
  const int tt = blockIdx.x;   // t-tile (0..7)
  const int h = blockIdx.y;
  const int b = blockIdx.z;
  const int tid = threadIdx.x;
  const __bf16* src = qkv + (size_t)b * T_DIM * QKV_LD + 2 * C_DIM + h * HD_DIM;
#pragma unroll
  for (int i = 0; i < 2; ++i) {
    int c = tid + i * 256;     // 512 chunks: row=t-in-tile, cc=d base
    int row = c >> 3, cc = (c & 7) * 8;
    *(bf16x8*)&Tl[row][cc] = *(const bf16x8*)&src[(size_t)(tt * 64 + row) * QKV_LD + cc];
  }
  __syncthreads();
  __bf16* dst = vt + (size_t)(b * NH_DIM + h) * HD_DIM * T_DIM + tt * 64;
#pragma unroll
  for (int i = 0; i < 2; ++i) {
    int c = tid + i * 256;     // drow=d, tc=t base
    int drow = c >> 3, tc = (c & 7) * 8;
    bf16x8 v;
#pragma unroll
    for (int j = 0; j < 8; ++j) v[j] = Tl[tc + j][drow];
    *(bf16x8*)&dst[(size_t)drow * T_DIM + tc] = v;
  }
}

// ------- causal flash attention: paired q-tiles, no-max softmax, MFMA rowsum -
// (R9-verified structure, unchanged except: 1-D grid + T1 XCD swizzle so the
// 4 pair-blocks sharing one (b,h)'s K/V land on the SAME XCD L2, adjacent in
// its chunk -> K/V fetched once per L2 instead of 4x across XCDs.)
__global__ __launch_bounds__(256) void attn_kernel(const __bf16* __restrict__ qkv,
                                                   const __bf16* __restrict__ vt,
                                                   __bf16* __restrict__ o) {
  __shared__ __attribute__((aligned(16))) __bf16 K0s[64 * 64];   // 8 KB each
  __shared__ __attribute__((aligned(16))) __bf16 K1s[64 * 64];
  __shared__ __attribute__((aligned(16))) __bf16 V0s[64 * 64];
  __shared__ __attribute__((aligned(16))) __bf16 V1s[64 * 64];
  // T1: 3072 blocks, 8 XCDs -> chunks of 384
  const int bid = blockIdx.x;
  const int swz = (bid & 7) * 384 + (bid >> 3);
  const int pair = swz & 3;                 // 0..3
  const int h = (swz >> 2) % NH_DIM;
  const int b = swz / (4 * NH_DIM);
  const int qlo = pair, qhi = 7 - pair;
  const int tid = threadIdx.x;
  const int wave = tid >> 6;
  const int lane = tid & 63;
  const int lr = lane & 15;
  const int quad = lane >> 4;
  const __bf16* qbase = qkv + (size_t)b * T_DIM * QKV_LD + h * HD_DIM;
  const __bf16* kbase = qbase + C_DIM;
  const __bf16* vtb = vt + (size_t)(b * NH_DIM + h) * HD_DIM * T_DIM;  // [d][t]
  const int qrow_lo = qlo * 64 + wave * 16;
  const int qrow_hi = qhi * 64 + wave * 16;
  // Q fragments, both strips: [idx=lane&15][k=quad*8+j]
  bf16x8 qfl[2], qfh[2];
#pragma unroll
  for (int ks = 0; ks < 2; ++ks) {
    qfl[ks] = *(const bf16x8*)&qbase[(size_t)(qrow_lo + lr) * QKV_LD + ks * 32 + quad * 8];
    qfh[ks] = *(const bf16x8*)&qbase[(size_t)(qrow_hi + lr) * QKV_LD + ks * 32 + quad * 8];
  }
  f32x4 oaL[4] = {}, oaH[4] = {};
  f32x4 lL = {}, lH = {};
  bf16x8 vones;
#pragma unroll
  for (int e = 0; e < 8; ++e) vones[e] = (__bf16)1.0f;
  const int skey = (((lane >> 3) & 3) << 1) | (wave & 1);
  const int gsl = ((lane & 7) ^ skey) * 8;  // global col (elements)
  const int grA = wave * 8 + (lane >> 3);
  const int grB = grA + 32;
  const int ldsA = wave * 512;        // elements
  const int ldsB = (wave + 4) * 512;
  auto stage = [&](int kt, __bf16* KT, __bf16* VT) {
    const __bf16* ks = kbase + (size_t)(kt * 64) * QKV_LD;
    const __bf16* vs = vtb + kt * 64;
    gload_lds16(&ks[(size_t)grA * QKV_LD + gsl], KT + ldsA);
    gload_lds16(&ks[(size_t)grB * QKV_LD + gsl], KT + ldsB);
    gload_lds16(&vs[(size_t)grA * T_DIM + gsl], VT + ldsA);
    gload_lds16(&vs[(size_t)grB * T_DIM + gsl], VT + ldsB);
  };
  const int keyK = ((lr & 3) << 1) | ((lr >> 2) & 1);
  const int keyV = ((lr & 3) << 1) | ((lr >> 3) & 1);
  const int swK0 = (quad ^ keyK) * 8, swK1 = ((4 + quad) ^ keyK) * 8;
  const int swV0 = (quad ^ keyV) * 8, swV1 = ((4 + quad) ^ keyV) * 8;
  const int rkbase = ((lr >> 2) & 3) * 8 + (lr & 3);  // sigma row base for this lane
  auto body = [&](const __bf16* KT, const __bf16* VT, const bf16x8 (&qf)[2],
                  f32x4 (&oa)[4], f32x4& lacc, int myq, bool diag, int kt) {
    f32x4 sj[4];
#pragma unroll
    for (int j = 0; j < 4; ++j) {
      const int rK = (j >> 1) * 32 + (j & 1) * 4 + rkbase;
      bf16x8 kf0 = *(const bf16x8*)&KT[rK * 64 + swK0];
      bf16x8 kf1 = *(const bf16x8*)&KT[rK * 64 + swK1];
      f32x4 z = {};
      z = __builtin_amdgcn_mfma_f32_16x16x32_bf16(kf0, qf[0], z, 0, 0, 0);
      z = __builtin_amdgcn_mfma_f32_16x16x32_bf16(kf1, qf[1], z, 0, 0, 0);
      sj[j] = z;
    }
    if (diag) {
#pragma unroll
      for (int j = 0; j < 4; ++j)
#pragma unroll
        for (int r = 0; r < 4; ++r) {
          int key = kt * 64 + (j >> 1) * 32 + quad * 8 + (j & 1) * 4 + r;
          if (key > myq) sj[j][r] = -3.0e38f;  // exp2 -> 0
        }
    }
    bf16x8 pf0, pf1;
#pragma unroll
    for (int j = 0; j < 4; ++j)
#pragma unroll
      for (int r = 0; r < 4; ++r) {
        float pv = exp2f(sj[j][r]);
        const int jj = (j & 1) * 4 + r;
        if (j < 2) pf0[jj] = (__bf16)pv; else pf1[jj] = (__bf16)pv;
      }
#pragma unroll
    for (int dt = 0; dt < 4; ++dt) {
      bf16x8 vf0 = *(const bf16x8*)&VT[(dt * 16 + lr) * 64 + swV0];
      bf16x8 vf1 = *(const bf16x8*)&VT[(dt * 16 + lr) * 64 + swV1];
      oa[dt] = __builtin_amdgcn_mfma_f32_16x16x32_bf16(pf0, vf0, oa[dt], 0, 0, 0);
      oa[dt] = __builtin_amdgcn_mfma_f32_16x16x32_bf16(pf1, vf1, oa[dt], 0, 0, 0);
    }
    lacc = __builtin_amdgcn_mfma_f32_16x16x32_bf16(pf0, vones, lacc, 0, 0, 0);
    lacc = __builtin_amdgcn_mfma_f32_16x16x32_bf16(pf1, vones, lacc, 0, 0, 0);
  };
  // prologue
  stage(0, K0s, V0s);
  __syncthreads();  // drains DMA -> tile 0 ready
  int kt = 0;
  while (true) {
    if (kt < qhi) stage(kt + 1, K1s, V1s);
    if (kt <= qlo) body(K0s, V0s, qfl, oaL, lL, qrow_lo + lr, kt == qlo, kt);
    body(K0s, V0s, qfh, oaH, lH, qrow_hi + lr, kt == qhi, kt);
    __syncthreads();  // drains kt+1 DMA; guards buf0 reuse
    ++kt;
    if (kt > qhi) break;
    if (kt < qhi) stage(kt + 1, K0s, V0s);
    if (kt <= qlo) body(K1s, V1s, qfl, oaL, lL, qrow_lo + lr, kt == qlo, kt);
    body(K1s, V1s, qfh, oaH, lH, qrow_hi + lr, kt == qhi, kt);
    __syncthreads();
    ++kt;
    if (kt > qhi) break;
  }
  // epilogue: lacc[r] is already l of q-row quad*4+r -> direct divide, no shfl
#pragma unroll
  for (int r = 0; r < 4; ++r) {
    float ilL = 1.0f / lL[r];
    float ilH = 1.0f / lH[r];
#pragma unroll
    for (int dt = 0; dt < 4; ++dt) {
      size_t rowL = (size_t)b * T_DIM + qrow_lo + quad * 4 + r;
      size_t rowH = (size_t)b * T_DIM + qrow_hi + quad * 4 + r;
      o[rowL * C_DIM + h * HD_DIM + dt * 16 + lr] = (__bf16)(oaL[dt][r] * ilL);
      o[rowH * C_DIM + h * HD_DIM + dt * 16 + lr] = (__bf16)(oaH[dt][r] * ilH);
    }
  }
}

extern "C" void kernel_launch(void* const* d_in, const int* in_sizes, int n_in,
                              void* d_out, int out_size, void* d_ws, size_t ws_size,
                              hipStream_t stream) {
  const float* x    = (const float*)d_in[0];  // [B,T,C]
  const float* wqkv = (const float*)d_in[1];  // [3C,C]
  const float* wout = (const float*)d_in[2];  // [C,C]
  const float* cosp = (const float*)d_in[3];  // [1,1,512,8]
  const float* sinp = (const float*)d_in[4];  // [1,1,512,8]
  float* out = (float*)d_out;

  char* ws = (char*)d_ws;
  // xb's old region now holds only vt (x is consumed fp32 directly by gemm1)
  __bf16* vtb   = (__bf16*)(ws);                    // 25165824 elems (50331648 B)
  __bf16* wqkvb = (__bf16*)(ws + 50331648);         // 442368
  __bf16* woutb = (__bf16*)(ws + 51216384);         // 147456
  __bf16* qkvb  = (__bf16*)(ws + 51511296);         // 75497472
  __bf16* ob    = (__bf16*)(ws + 202506240);        // 25165824
  // total ws use: 252837888 bytes

  const int M = B_DIM * T_DIM;  // 65536

  // weight casts only (147456 float4 units = 576 blocks); x-cast fused in gemm1
  cast_w<<<576, 256, 0, stream>>>(wqkv, wout, wqkvb, woutb);

  // qkv = x @ Wqkv^T : [65536][1152] bf16, fp32-A fused cast + RoPE + Q*K_SCALE
  gemm_bt<<<dim3(QKV_LD / 128, M / 128), 256, 0, stream>>>(
      (const __bf16*)nullptr, x, wqkvb, qkvb, (float*)nullptr, cosp, sinp,
      M, QKV_LD, C_DIM);

  // V -> vt[b][h][d][t]
  transpose_v<<<dim3(T_DIM / 64, NH_DIM, B_DIM), 256, 0, stream>>>(qkvb, vtb);

  // causal flash attention -> o [65536][384] bf16 (1-D grid, T1 XCD swizzle)
  attn_kernel<<<3072, 256, 0, stream>>>(qkvb, vtb, ob);

  // out = o @ Wout^T : fp32 (bf16-A DMA path)
  gemm_bt<<<dim3(C_DIM / 128, M / 128), 256, 0, stream>>>(
      ob, (const float*)nullptr, woutb, (__bf16*)nullptr, out,
      (const float*)nullptr, (const float*)nullptr, M, C_DIM, C_DIM);
}

// Round 12
// 401.423 us; speedup vs baseline: 1.0342x; 1.0342x over previous
//
#include <hip/hip_runtime.h>

#define B_DIM 128
#define T_DIM 512
#define C_DIM 384
#define NH_DIM 6
#define HD_DIM 64
#define QKV_LD 1152  // 3*C

typedef __bf16 bf16x8 __attribute__((ext_vector_type(8)));
typedef __bf16 bf16x4 __attribute__((ext_vector_type(4)));
typedef float f32x4 __attribute__((ext_vector_type(4)));

// (1/sqrt(64)) * log2(e): folded into Q inside gemm1's epilogue, so attention
// scores come out of QK^T already in the exp2 domain.
#define K_SCALE 0.18033688011112042f

// direct global->LDS DMA, 16B per lane. LDS dest is wave-uniform base +
// lane*16 (m104); the global source is per-lane, which is how the k-slot
// swizzle is applied (m173 pattern).
__device__ __forceinline__ void gload_lds16(const __bf16* g, __bf16* l) {
  __builtin_amdgcn_global_load_lds(
      (const __attribute__((address_space(1))) void*)g,
      (__attribute__((address_space(3))) void*)l, 16, 0, 0);
}

// ---------------- fused fp32 -> bf16 cast for x, Wqkv, Wout ----------------
// RESTORED (R11 post-mortem): fusing x's cast into gemm1 forced gemm1 to eat
// the cold ~900cy HBM read of x with only ~160cy of MFMA to hide it (116->152
// regression). The standalone cast streams x at full BW with huge TLP and
// gemm1 then DMAs warm bf16.
#define X_F4 6291456
#define WQKV_F4 110592
#define WOUT_F4 36864
__global__ __launch_bounds__(256) void cast_all(const float* __restrict__ x,
                                                const float* __restrict__ wqkv,
                                                const float* __restrict__ wout,
                                                __bf16* __restrict__ xb,
                                                __bf16* __restrict__ wqkvb,
                                                __bf16* __restrict__ woutb) {
  int i = blockIdx.x * blockDim.x + threadIdx.x;
  const float4* src;
  bf16x4* dst;
  if (i < X_F4) {
    src = (const float4*)x + i;
    dst = (bf16x4*)xb + i;
  } else if (i < X_F4 + WQKV_F4) {
    src = (const float4*)wqkv + (i - X_F4);
    dst = (bf16x4*)wqkvb + (i - X_F4);
  } else {
    src = (const float4*)wout + (i - X_F4 - WQKV_F4);
    dst = (bf16x4*)woutb + (i - X_F4 - WQKV_F4);
  }
  float4 v = *src;
  bf16x4 o;
  o[0] = (__bf16)v.x; o[1] = (__bf16)v.y; o[2] = (__bf16)v.z; o[3] = (__bf16)v.w;
  *dst = o;
}

// ---------------- C = A * B^T  (+ fused RoPE & Q pre-scale) ----------------
// A[M][K] bf16 row-major (DMA-staged), B[N][K] bf16. C -> bf16 Cb or fp32 Cf.
// T1 XCD SWIZZLE (R11-verified: gemm1 FETCH 216 -> 62 MB): consecutive
// dispatch ids round-robin across the 8 XCD L2s, so the 9 consecutive blocks
// sharing an A-panel each re-fetched it. Remap swz = (bid&7)*(nwg/8) + bid>>3
// -> each XCD gets a contiguous chunk of the n-fastest order; A-panel fetched
// once per XCD L2 and DMA waits hit L2 (~200cy) instead of HBM (~900cy).
// nwg must be %8==0 (4608, 1536 both are).
// Staging: global_load_lds width=16, LINEAR [128][32] tiles, both-sides XOR
// k-slot swizzle keyed on (row>>1)&3 -> 2-way alias = free (m136).
__global__ __launch_bounds__(256) void gemm_bt(const __bf16* __restrict__ A,
                                               const __bf16* __restrict__ Bm,
                                               __bf16* __restrict__ Cb,
                                               float* __restrict__ Cf,
                                               const float* __restrict__ cosp,
                                               const float* __restrict__ sinp,
                                               int M, int N, int K) {
  __shared__ __attribute__((aligned(16))) __bf16 As[128 * 32];  // 8 KB
  __shared__ __attribute__((aligned(16))) __bf16 Bs[128 * 32];  // 8 KB
  const int nwg = gridDim.x * gridDim.y;
  const int bid = blockIdx.x + gridDim.x * blockIdx.y;  // dispatch order (x fastest)
  const int per = nwg >> 3;
  const int swz = (bid & 7) * per + (bid >> 3);         // T1, bijective (nwg%8==0)
  const int m0 = (swz / gridDim.x) * 128;
  const int n0 = (swz % gridDim.x) * 128;
  const int tid = threadIdx.x;
  const int wave = tid >> 6;
  const int lane = tid & 63;
  const int lr = lane & 15;
  const int quad = lane >> 4;
  const int wm = (wave & 1) * 64;
  const int wn = (wave >> 1) * 64;
  const int ca0 = wave * 2, ca1 = wave * 2 + 1;
  const int srow = lane >> 2;
  const int row0 = ca0 * 16 + srow, row1 = ca1 * 16 + srow;
  const int slot = (lane & 3) ^ ((lane >> 3) & 3);  // (l&3) ^ ((srow>>1)&3)
  const int rs = (quad ^ ((lr >> 1) & 3)) * 8;
  f32x4 acc[4][4] = {};
  for (int k0 = 0; k0 < K; k0 += 32) {
    __syncthreads();  // prev iteration's LDS reads done
    gload_lds16(&A[(size_t)(m0 + row0) * K + k0 + slot * 8], &As[ca0 * 512]);
    gload_lds16(&A[(size_t)(m0 + row1) * K + k0 + slot * 8], &As[ca1 * 512]);
    gload_lds16(&Bm[(size_t)(n0 + row0) * K + k0 + slot * 8], &Bs[ca0 * 512]);
    gload_lds16(&Bm[(size_t)(n0 + row1) * K + k0 + slot * 8], &Bs[ca1 * 512]);
    __syncthreads();  // compiler drains vmcnt before the barrier
    bf16x8 af[4], bf[4];
#pragma unroll
    for (int i = 0; i < 4; ++i)
      af[i] = *(bf16x8*)&As[(wm + i * 16 + lr) * 32 + rs];
#pragma unroll
    for (int j = 0; j < 4; ++j)
      bf[j] = *(bf16x8*)&Bs[(wn + j * 16 + lr) * 32 + rs];
#pragma unroll
    for (int i = 0; i < 4; ++i)
#pragma unroll
      for (int j = 0; j < 4; ++j)
        acc[i][j] = __builtin_amdgcn_mfma_f32_16x16x32_bf16(af[i], bf[j], acc[i][j], 0, 0, 0);
  }
  // D layout: col = lane&15, row = quad*4 + r  (m89-verified)
  const bool doRope = (cosp != nullptr);
#pragma unroll
  for (int i = 0; i < 4; ++i) {
#pragma unroll
    for (int j = 0; j < 4; ++j) {
      int gm = m0 + wm + i * 16 + quad * 4;
      int gn = n0 + wn + j * 16 + lr;
      if (Cf) {
#pragma unroll
        for (int r = 0; r < 4; ++r) Cf[(size_t)(gm + r) * N + gn] = acc[i][j][r];
      } else {
        const int cbase = n0 + wn + j * 16;
        const bool ropeBlk = doRope && (cbase < 2 * C_DIM) && ((cbase & 63) == 0);
        const float qs = (doRope && cbase < C_DIM) ? K_SCALE : 1.0f;
        if (ropeBlk) {
#pragma unroll
          for (int r = 0; r < 4; ++r) {
            float v = acc[i][j][r];
            float p = __shfl_xor(v, 8, 64);  // partner dim (d <-> d+8), same quad
            int t = (gm + r) & (T_DIM - 1);
            float c = cosp[t * 8 + (lr & 7)];
            float s = sinp[t * 8 + (lr & 7)];
            v = (lr & 8) ? __builtin_fmaf(v, c, p * s)
                         : __builtin_fmaf(v, c, -p * s);
            Cb[(size_t)(gm + r) * N + gn] = (__bf16)(v * qs);
          }
        } else {
#pragma unroll
          for (int r = 0; r < 4; ++r)
            Cb[(size_t)(gm + r) * N + gn] = (__bf16)(acc[i][j][r] * qs);
        }
      }
    }
  }
}

// ---------------- V transpose: vt[b][h][d][t] <- qkv[b*T+t][768 + h*64 + d] ----------------
__global__ __launch_bounds__(256) void transpose_v(const __bf16* __restrict__ qkv,
                                                   __bf16* __restrict__ vt) {
  __shared__ __attribute__((aligned(16))) __bf16 Tl[64][72];
  const int tt = blockIdx.x;   // t-tile (0..7)
  const int h = blockIdx.y;
  const int b = blockIdx.z;
  const int tid = threadIdx.x;
  const __bf16* src = qkv + (size_t)b * T_DIM * QKV_LD + 2 * C_DIM + h * HD_DIM;
#pragma unroll
  for (int i = 0; i < 2; ++i) {
    int c = tid + i * 256;     // 512 chunks: row=t-in-tile, cc=d base
    int row = c >> 3, cc = (c & 7) * 8;
    *(bf16x8*)&Tl[row][cc] = *(const bf16x8*)&src[(size_t)(tt * 64 + row) * QKV_LD + cc];
  }
  __syncthreads();
  __bf16* dst = vt + (size_t)(b * NH_DIM + h) * HD_DIM * T_DIM + tt * 64;
#pragma unroll
  for (int i = 0; i < 2; ++i) {
    int c = tid + i * 256;     // drow=d, tc=t base
    int drow = c >> 3, tc = (c & 7) * 8;
    bf16x8 v;
#pragma unroll
    for (int j = 0; j < 8; ++j) v[j] = Tl[tc + j][drow];
    *(bf16x8*)&dst[(size_t)drow * T_DIM + tc] = v;
  }
}

// ------- causal flash attention: paired q-tiles, no-max softmax, MFMA rowsum -
// (R9-verified structure + R11 T1 XCD swizzle: the 4 pair-blocks sharing one
// (b,h)'s K/V land adjacent on the same XCD L2.)
__global__ __launch_bounds__(256) void attn_kernel(const __bf16* __restrict__ qkv,
                                                   const __bf16* __restrict__ vt,
                                                   __bf16* __restrict__ o) {
  __shared__ __attribute__((aligned(16))) __bf16 K0s[64 * 64];   // 8 KB each
  __shared__ __attribute__((aligned(16))) __bf16 K1s[64 * 64];
  __shared__ __attribute__((aligned(16))) __bf16 V0s[64 * 64];
  __shared__ __attribute__((aligned(16))) __bf16 V1s[64 * 64];
  // T1: 3072 blocks, 8 XCDs -> chunks of 384
  const int bid = blockIdx.x;
  const int swz = (bid & 7) * 384 + (bid >> 3);
  const int pair = swz & 3;                 // 0..3
  const int h = (swz >> 2) % NH_DIM;
  const int b = swz / (4 * NH_DIM);
  const int qlo = pair, qhi = 7 - pair;
  const int tid = threadIdx.x;
  const int wave = tid >> 6;
  const int lane = tid & 63;
  const int lr = lane & 15;
  const int quad = lane >> 4;
  const __bf16* qbase = qkv + (size_t)b * T_DIM * QKV_LD + h * HD_DIM;
  const __bf16* kbase = qbase + C_DIM;
  const __bf16* vtb = vt + (size_t)(b * NH_DIM + h) * HD_DIM * T_DIM;  // [d][t]
  const int qrow_lo = qlo * 64 + wave * 16;
  const int qrow_hi = qhi * 64 + wave * 16;
  // Q fragments, both strips: [idx=lane&15][k=quad*8+j]
  bf16x8 qfl[2], qfh[2];
#pragma unroll
  for (int ks = 0; ks < 2; ++ks) {
    qfl[ks] = *(const bf16x8*)&qbase[(size_t)(qrow_lo + lr) * QKV_LD + ks * 32 + quad * 8];
    qfh[ks] = *(const bf16x8*)&qbase[(size_t)(qrow_hi + lr) * QKV_LD + ks * 32 + quad * 8];
  }
  f32x4 oaL[4] = {}, oaH[4] = {};
  f32x4 lL = {}, lH = {};
  bf16x8 vones;
#pragma unroll
  for (int e = 0; e < 8; ++e) vones[e] = (__bf16)1.0f;
  const int skey = (((lane >> 3) & 3) << 1) | (wave & 1);
  const int gsl = ((lane & 7) ^ skey) * 8;  // global col (elements)
  const int grA = wave * 8 + (lane >> 3);
  const int grB = grA + 32;
  const int ldsA = wave * 512;        // elements
  const int ldsB = (wave + 4) * 512;
  auto stage = [&](int kt, __bf16* KT, __bf16* VT) {
    const __bf16* ks = kbase + (size_t)(kt * 64) * QKV_LD;
    const __bf16* vs = vtb + kt * 64;
    gload_lds16(&ks[(size_t)grA * QKV_LD + gsl], KT + ldsA);
    gload_lds16(&ks[(size_t)grB * QKV_LD + gsl], KT + ldsB);
    gload_lds16(&vs[(size_t)grA * T_DIM + gsl], VT + ldsA);
    gload_lds16(&vs[(size_t)grB * T_DIM + gsl], VT + ldsB);
  };
  const int keyK = ((lr & 3) << 1) | ((lr >> 2) & 1);
  const int keyV = ((lr & 3) << 1) | ((lr >> 3) & 1);
  const int swK0 = (quad ^ keyK) * 8, swK1 = ((4 + quad) ^ keyK) * 8;
  const int swV0 = (quad ^ keyV) * 8, swV1 = ((4 + quad) ^ keyV) * 8;
  const int rkbase = ((lr >> 2) & 3) * 8 + (lr & 3);  // sigma row base for this lane
  auto body = [&](const __bf16* KT, const __bf16* VT, const bf16x8 (&qf)[2],
                  f32x4 (&oa)[4], f32x4& lacc, int myq, bool diag, int kt) {
    f32x4 sj[4];
#pragma unroll
    for (int j = 0; j < 4; ++j) {
      const int rK = (j >> 1) * 32 + (j & 1) * 4 + rkbase;
      bf16x8 kf0 = *(const bf16x8*)&KT[rK * 64 + swK0];
      bf16x8 kf1 = *(const bf16x8*)&KT[rK * 64 + swK1];
      f32x4 z = {};
      z = __builtin_amdgcn_mfma_f32_16x16x32_bf16(kf0, qf[0], z, 0, 0, 0);
      z = __builtin_amdgcn_mfma_f32_16x16x32_bf16(kf1, qf[1], z, 0, 0, 0);
      sj[j] = z;
    }
    if (diag) {
#pragma unroll
      for (int j = 0; j < 4; ++j)
#pragma unroll
        for (int r = 0; r < 4; ++r) {
          int key = kt * 64 + (j >> 1) * 32 + quad * 8 + (j & 1) * 4 + r;
          if (key > myq) sj[j][r] = -3.0e38f;  // exp2 -> 0
        }
    }
    bf16x8 pf0, pf1;
#pragma unroll
    for (int j = 0; j < 4; ++j)
#pragma unroll
      for (int r = 0; r < 4; ++r) {
        float pv = exp2f(sj[j][r]);
        const int jj = (j & 1) * 4 + r;
        if (j < 2) pf0[jj] = (__bf16)pv; else pf1[jj] = (__bf16)pv;
      }
#pragma unroll
    for (int dt = 0; dt < 4; ++dt) {
      bf16x8 vf0 = *(const bf16x8*)&VT[(dt * 16 + lr) * 64 + swV0];
      bf16x8 vf1 = *(const bf16x8*)&VT[(dt * 16 + lr) * 64 + swV1];
      oa[dt] = __builtin_amdgcn_mfma_f32_16x16x32_bf16(pf0, vf0, oa[dt], 0, 0, 0);
      oa[dt] = __builtin_amdgcn_mfma_f32_16x16x32_bf16(pf1, vf1, oa[dt], 0, 0, 0);
    }
    lacc = __builtin_amdgcn_mfma_f32_16x16x32_bf16(pf0, vones, lacc, 0, 0, 0);
    lacc = __builtin_amdgcn_mfma_f32_16x16x32_bf16(pf1, vones, lacc, 0, 0, 0);
  };
  // prologue
  stage(0, K0s, V0s);
  __syncthreads();  // drains DMA -> tile 0 ready
  int kt = 0;
  while (true) {
    if (kt < qhi) stage(kt + 1, K1s, V1s);
    if (kt <= qlo) body(K0s, V0s, qfl, oaL, lL, qrow_lo + lr, kt == qlo, kt);
    body(K0s, V0s, qfh, oaH, lH, qrow_hi + lr, kt == qhi, kt);
    __syncthreads();  // drains kt+1 DMA; guards buf0 reuse
    ++kt;
    if (kt > qhi) break;
    if (kt < qhi) stage(kt + 1, K0s, V0s);
    if (kt <= qlo) body(K1s, V1s, qfl, oaL, lL, qrow_lo + lr, kt == qlo, kt);
    body(K1s, V1s, qfh, oaH, lH, qrow_hi + lr, kt == qhi, kt);
    __syncthreads();
    ++kt;
    if (kt > qhi) break;
  }
  // epilogue: lacc[r] is already l of q-row quad*4+r -> direct divide, no shfl
#pragma unroll
  for (int r = 0; r < 4; ++r) {
    float ilL = 1.0f / lL[r];
    float ilH = 1.0f / lH[r];
#pragma unroll
    for (int dt = 0; dt < 4; ++dt) {
      size_t rowL = (size_t)b * T_DIM + qrow_lo + quad * 4 + r;
      size_t rowH = (size_t)b * T_DIM + qrow_hi + quad * 4 + r;
      o[rowL * C_DIM + h * HD_DIM + dt * 16 + lr] = (__bf16)(oaL[dt][r] * ilL);
      o[rowH * C_DIM + h * HD_DIM + dt * 16 + lr] = (__bf16)(oaH[dt][r] * ilH);
    }
  }
}

extern "C" void kernel_launch(void* const* d_in, const int* in_sizes, int n_in,
                              void* d_out, int out_size, void* d_ws, size_t ws_size,
                              hipStream_t stream) {
  const float* x    = (const float*)d_in[0];  // [B,T,C]
  const float* wqkv = (const float*)d_in[1];  // [3C,C]
  const float* wout = (const float*)d_in[2];  // [C,C]
  const float* cosp = (const float*)d_in[3];  // [1,1,512,8]
  const float* sinp = (const float*)d_in[4];  // [1,1,512,8]
  float* out = (float*)d_out;

  char* ws = (char*)d_ws;
  __bf16* xb    = (__bf16*)(ws);                    // 25165824 elems (50331648 B)
  __bf16* wqkvb = (__bf16*)(ws + 50331648);         // 442368
  __bf16* woutb = (__bf16*)(ws + 51216384);         // 147456
  __bf16* qkvb  = (__bf16*)(ws + 51511296);         // 75497472
  __bf16* ob    = (__bf16*)(ws + 202506240);        // 25165824
  // vt reuses xb's region: xb is dead once the QKV GEMM has completed, and
  // transpose_v runs strictly after it on the same stream. Exact fit: 50331648 B.
  __bf16* vtb   = xb;
  // total ws use: 252837888 bytes

  const int M = B_DIM * T_DIM;  // 65536

  // fused casts: 6291456 + 110592 + 36864 = 6438912 float4 units = 25152 blocks
  cast_all<<<25152, 256, 0, stream>>>(x, wqkv, wout, xb, wqkvb, woutb);

  // qkv = x @ Wqkv^T : [65536][1152] bf16, RoPE + Q*K_SCALE fused (T1 swizzle)
  gemm_bt<<<dim3(QKV_LD / 128, M / 128), 256, 0, stream>>>(
      xb, wqkvb, qkvb, (float*)nullptr, cosp, sinp, M, QKV_LD, C_DIM);

  // V -> vt[b][h][d][t] (xb region; xb dead after the QKV GEMM)
  transpose_v<<<dim3(T_DIM / 64, NH_DIM, B_DIM), 256, 0, stream>>>(qkvb, vtb);

  // causal flash attention -> o [65536][384] bf16 (1-D grid, T1 XCD swizzle)
  attn_kernel<<<3072, 256, 0, stream>>>(qkvb, vtb, ob);

  // out = o @ Wout^T : fp32 (T1 swizzle)
  gemm_bt<<<dim3(C_DIM / 128, M / 128), 256, 0, stream>>>(
      ob, woutb, (__bf16*)nullptr, out, (const float*)nullptr, (const float*)nullptr,
      M, C_DIM, C_DIM);
}

// Round 13
// 372.520 us; speedup vs baseline: 1.1144x; 1.0776x over previous
//
#include <hip/hip_runtime.h>

#define B_DIM 128
#define T_DIM 512
#define C_DIM 384
#define NH_DIM 6
#define HD_DIM 64
#define QKV_LD 1152  // 3*C

typedef __bf16 bf16x8 __attribute__((ext_vector_type(8)));
typedef __bf16 bf16x4 __attribute__((ext_vector_type(4)));
typedef float f32x4 __attribute__((ext_vector_type(4)));

// (1/sqrt(64)) * log2(e): folded into Q inside gemm1's epilogue, so attention
// scores come out of QK^T already in the exp2 domain.
#define K_SCALE 0.18033688011112042f

// direct global->LDS DMA, 16B per lane. LDS dest is wave-uniform base +
// lane*16 (m104); the global source is per-lane, which is how the k-slot
// swizzle is applied (m173 pattern).
__device__ __forceinline__ void gload_lds16(const __bf16* g, __bf16* l) {
  __builtin_amdgcn_global_load_lds(
      (const __attribute__((address_space(1))) void*)g,
      (__attribute__((address_space(3))) void*)l, 16, 0, 0);
}

// ---------------- fused fp32 -> bf16 cast for x, Wqkv, Wout ----------------
#define X_F4 6291456
#define WQKV_F4 110592
#define WOUT_F4 36864
__global__ __launch_bounds__(256) void cast_all(const float* __restrict__ x,
                                                const float* __restrict__ wqkv,
                                                const float* __restrict__ wout,
                                                __bf16* __restrict__ xb,
                                                __bf16* __restrict__ wqkvb,
                                                __bf16* __restrict__ woutb) {
  int i = blockIdx.x * blockDim.x + threadIdx.x;
  const float4* src;
  bf16x4* dst;
  if (i < X_F4) {
    src = (const float4*)x + i;
    dst = (bf16x4*)xb + i;
  } else if (i < X_F4 + WQKV_F4) {
    src = (const float4*)wqkv + (i - X_F4);
    dst = (bf16x4*)wqkvb + (i - X_F4);
  } else {
    src = (const float4*)wout + (i - X_F4 - WQKV_F4);
    dst = (bf16x4*)woutb + (i - X_F4 - WQKV_F4);
  }
  float4 v = *src;
  bf16x4 o;
  o[0] = (__bf16)v.x; o[1] = (__bf16)v.y; o[2] = (__bf16)v.z; o[3] = (__bf16)v.w;
  *dst = o;
}

// ---------------- C = A * B^T  (split q/k/v^T epilogue) --------------------
// A[M][K] bf16 row-major (DMA-staged), B[N][K] bf16. Outputs:
//  * generic: Cf fp32 [M][N] (gemm2)
//  * qkv mode (Cbq != null): block routes by n0 (tile-aligned):
//      n0 <  384 : q -> Cbq[M][384], *K_SCALE, rope on (col&63)<16 blocks
//      n0 <  768 : k -> Cbk[M][384], rope on (col&63)<16 blocks
//      n0 >= 768 : v -> vt[(b*6+h)*64+d][t]  TRANSPOSED via in-block LDS
//    The vt path deletes the standalone transpose_v kernel (50MB R + 50MB W
//    of HBM traffic + a launch). As/Bs (2x8KB) are reused as the transpose
//    scratch: 2 waves per pass x 2 passes, XOR slot swizzle (store 2-way
//    alias = free; read = dense-minimum).
// T1 XCD swizzle (R11/R12-verified: gemm1 FETCH 216 -> 32 MB). Staging:
// global_load_lds width=16, LINEAR [128][32] tiles, both-sides XOR k-slot
// swizzle keyed on (row>>1)&3 -> 2-way alias = free (m136). Staging pointers
// hoisted out of the K-loop (VALUBusy was 62%).
__global__ __launch_bounds__(256) void gemm_bt(const __bf16* __restrict__ A,
                                               const __bf16* __restrict__ Bm,
                                               __bf16* __restrict__ Cbq,
                                               __bf16* __restrict__ Cbk,
                                               __bf16* __restrict__ vt,
                                               float* __restrict__ Cf,
                                               const float* __restrict__ cosp,
                                               const float* __restrict__ sinp,
                                               int M, int N, int K) {
  __shared__ __attribute__((aligned(16))) __bf16 As[128 * 32];  // 8 KB
  __shared__ __attribute__((aligned(16))) __bf16 Bs[128 * 32];  // 8 KB
  const int nwg = gridDim.x * gridDim.y;
  const int bid = blockIdx.x + gridDim.x * blockIdx.y;  // dispatch order (x fastest)
  const int per = nwg >> 3;
  const int swz = (bid & 7) * per + (bid >> 3);         // T1, bijective (nwg%8==0)
  const int m0 = (swz / gridDim.x) * 128;
  const int n0 = (swz % gridDim.x) * 128;
  const int tid = threadIdx.x;
  const int wave = tid >> 6;
  const int lane = tid & 63;
  const int lr = lane & 15;
  const int quad = lane >> 4;
  const int wm = (wave & 1) * 64;
  const int wn = (wave >> 1) * 64;
  const int ca0 = wave * 2, ca1 = wave * 2 + 1;
  const int srow = lane >> 2;
  const int row0 = ca0 * 16 + srow, row1 = ca1 * 16 + srow;
  const int slot = (lane & 3) ^ ((lane >> 3) & 3);  // (l&3) ^ ((srow>>1)&3)
  const int rs = (quad ^ ((lr >> 1) & 3)) * 8;
  // hoisted staging pointers (advance 32 elems per K-step)
  const __bf16* pA0 = &A[(size_t)(m0 + row0) * K + slot * 8];
  const __bf16* pA1 = &A[(size_t)(m0 + row1) * K + slot * 8];
  const __bf16* pB0 = &Bm[(size_t)(n0 + row0) * K + slot * 8];
  const __bf16* pB1 = &Bm[(size_t)(n0 + row1) * K + slot * 8];
  f32x4 acc[4][4] = {};
  for (int k0 = 0; k0 < K; k0 += 32) {
    __syncthreads();  // prev iteration's LDS reads done
    gload_lds16(pA0, &As[ca0 * 512]);
    gload_lds16(pA1, &As[ca1 * 512]);
    gload_lds16(pB0, &Bs[ca0 * 512]);
    gload_lds16(pB1, &Bs[ca1 * 512]);
    pA0 += 32; pA1 += 32; pB0 += 32; pB1 += 32;
    __syncthreads();  // compiler drains vmcnt before the barrier
    bf16x8 af[4], bf[4];
#pragma unroll
    for (int i = 0; i < 4; ++i)
      af[i] = *(bf16x8*)&As[(wm + i * 16 + lr) * 32 + rs];
#pragma unroll
    for (int j = 0; j < 4; ++j)
      bf[j] = *(bf16x8*)&Bs[(wn + j * 16 + lr) * 32 + rs];
#pragma unroll
    for (int i = 0; i < 4; ++i)
#pragma unroll
      for (int j = 0; j < 4; ++j)
        acc[i][j] = __builtin_amdgcn_mfma_f32_16x16x32_bf16(af[i], bf[j], acc[i][j], 0, 0, 0);
  }
  // D layout: col = lane&15, row = quad*4 + r  (m89-verified)
  if (Cf) {  // generic fp32 path (gemm2)
#pragma unroll
    for (int i = 0; i < 4; ++i)
#pragma unroll
      for (int j = 0; j < 4; ++j) {
        int gm = m0 + wm + i * 16 + quad * 4;
        int gn = n0 + wn + j * 16 + lr;
#pragma unroll
        for (int r = 0; r < 4; ++r) Cf[(size_t)(gm + r) * N + gn] = acc[i][j][r];
      }
    return;
  }
  if (n0 >= 2 * C_DIM) {
    // ---- V block: transpose 128x128 subtile -> vt[(b*6+h)*64+d][t] ----
    // per wave: 64 t (rows wm..) x 64 d (cols wn..) through an 8KB LDS region.
    // store: T[d*64 + (slot ^ (d&7))*8 + (t&7)], slot = t>>3 (XOR spreads
    // banks: 2-way = free). read: lane l, iter it: d = it*8 + (l>>3), 16B at
    // slot l&7 -> t-slot (l&7)^(l>>3) (lane-constant); 8-lane groups write
    // 128B-contiguous t segments.
    const int tbase = (m0 & (T_DIM - 1)) + wm;
    const int bb = m0 >> 9;                     // m0 / T_DIM
    const int dcolbase = n0 - 2 * C_DIM + wn;   // multiple of 64
    const int tslotx = (lane & 7) ^ (lane >> 3);
#pragma unroll
    for (int pass = 0; pass < 2; ++pass) {
      __syncthreads();  // pass0: main-loop LDS reads done; pass1: prev pair done
      if ((wave >> 1) == pass) {
        __bf16* T = (wave & 1) ? Bs : As;  // 4096 elems = 64x64
#pragma unroll
        for (int i = 0; i < 4; ++i)
#pragma unroll
          for (int j = 0; j < 4; ++j) {
            const int d = j * 16 + lr;
            const int sl = (i * 2 + (quad >> 1)) ^ (d & 7);
            bf16x4 w;
#pragma unroll
            for (int r = 0; r < 4; ++r) w[r] = (__bf16)acc[i][j][r];
            *(bf16x4*)&T[d * 64 + sl * 8 + (quad & 1) * 4] = w;
          }
        // same-wave DS ordering: compiler waits lgkmcnt before these reads
#pragma unroll
        for (int it = 0; it < 8; ++it) {
          const int dl = it * 8 + (lane >> 3);
          bf16x8 v = *(bf16x8*)&T[dl * 64 + (lane & 7) * 8];
          const int dfull = dcolbase + dl;
          const int hh = dfull >> 6, dd = dfull & 63;
          *(bf16x8*)&vt[((size_t)(bb * NH_DIM + hh) * 64 + dd) * T_DIM + tbase +
                        tslotx * 8] = v;
        }
      }
    }
    return;
  }
  // ---- q / k block: packed [M][384] write (+rope, +K_SCALE for q) ----
  const bool isQ = (n0 < C_DIM);
  __bf16* dst = isQ ? Cbq : Cbk;
  const int colbase = n0 - (isQ ? 0 : C_DIM);
  const float qs = isQ ? K_SCALE : 1.0f;
#pragma unroll
  for (int i = 0; i < 4; ++i) {
#pragma unroll
    for (int j = 0; j < 4; ++j) {
      int gm = m0 + wm + i * 16 + quad * 4;
      int gn = colbase + wn + j * 16 + lr;
      const int cbase = colbase + wn + j * 16;
      const bool ropeBlk = ((cbase & 63) == 0);
      if (ropeBlk) {
#pragma unroll
        for (int r = 0; r < 4; ++r) {
          float v = acc[i][j][r];
          float p = __shfl_xor(v, 8, 64);  // partner dim (d <-> d+8), same quad
          int t = (gm + r) & (T_DIM - 1);
          float c = cosp[t * 8 + (lr & 7)];
          float s = sinp[t * 8 + (lr & 7)];
          v = (lr & 8) ? __builtin_fmaf(v, c, p * s)
                       : __builtin_fmaf(v, c, -p * s);
          dst[(size_t)(gm + r) * C_DIM + gn] = (__bf16)(v * qs);
        }
      } else {
#pragma unroll
        for (int r = 0; r < 4; ++r)
          dst[(size_t)(gm + r) * C_DIM + gn] = (__bf16)(acc[i][j][r] * qs);
      }
    }
  }
}

// ------- causal flash attention: paired q-tiles, no-max softmax, MFMA rowsum -
// (R9 structure + R11 T1 XCD swizzle; q/k now from packed [M][384] buffers --
// row stride 768B instead of 2304B -> denser L2 lines.)
__global__ __launch_bounds__(256) void attn_kernel(const __bf16* __restrict__ qb,
                                                   const __bf16* __restrict__ kb,
                                                   const __bf16* __restrict__ vt,
                                                   __bf16* __restrict__ o) {
  __shared__ __attribute__((aligned(16))) __bf16 K0s[64 * 64];   // 8 KB each
  __shared__ __attribute__((aligned(16))) __bf16 K1s[64 * 64];
  __shared__ __attribute__((aligned(16))) __bf16 V0s[64 * 64];
  __shared__ __attribute__((aligned(16))) __bf16 V1s[64 * 64];
  // T1: 3072 blocks, 8 XCDs -> chunks of 384
  const int bid = blockIdx.x;
  const int swz = (bid & 7) * 384 + (bid >> 3);
  const int pair = swz & 3;                 // 0..3
  const int h = (swz >> 2) % NH_DIM;
  const int b = swz / (4 * NH_DIM);
  const int qlo = pair, qhi = 7 - pair;
  const int tid = threadIdx.x;
  const int wave = tid >> 6;
  const int lane = tid & 63;
  const int lr = lane & 15;
  const int quad = lane >> 4;
  const __bf16* qbase = qb + (size_t)b * T_DIM * C_DIM + h * HD_DIM;
  const __bf16* kbase = kb + (size_t)b * T_DIM * C_DIM + h * HD_DIM;
  const __bf16* vtb = vt + (size_t)(b * NH_DIM + h) * HD_DIM * T_DIM;  // [d][t]
  const int qrow_lo = qlo * 64 + wave * 16;
  const int qrow_hi = qhi * 64 + wave * 16;
  // Q fragments, both strips: [idx=lane&15][k=quad*8+j]
  bf16x8 qfl[2], qfh[2];
#pragma unroll
  for (int ks = 0; ks < 2; ++ks) {
    qfl[ks] = *(const bf16x8*)&qbase[(size_t)(qrow_lo + lr) * C_DIM + ks * 32 + quad * 8];
    qfh[ks] = *(const bf16x8*)&qbase[(size_t)(qrow_hi + lr) * C_DIM + ks * 32 + quad * 8];
  }
  f32x4 oaL[4] = {}, oaH[4] = {};
  f32x4 lL = {}, lH = {};
  bf16x8 vones;
#pragma unroll
  for (int e = 0; e < 8; ++e) vones[e] = (__bf16)1.0f;
  const int skey = (((lane >> 3) & 3) << 1) | (wave & 1);
  const int gsl = ((lane & 7) ^ skey) * 8;  // global col (elements)
  const int grA = wave * 8 + (lane >> 3);
  const int grB = grA + 32;
  const int ldsA = wave * 512;        // elements
  const int ldsB = (wave + 4) * 512;
  auto stage = [&](int kt, __bf16* KT, __bf16* VT) {
    const __bf16* ks = kbase + (size_t)(kt * 64) * C_DIM;
    const __bf16* vs = vtb + kt * 64;
    gload_lds16(&ks[(size_t)grA * C_DIM + gsl], KT + ldsA);
    gload_lds16(&ks[(size_t)grB * C_DIM + gsl], KT + ldsB);
    gload_lds16(&vs[(size_t)grA * T_DIM + gsl], VT + ldsA);
    gload_lds16(&vs[(size_t)grB * T_DIM + gsl], VT + ldsB);
  };
  const int keyK = ((lr & 3) << 1) | ((lr >> 2) & 1);
  const int keyV = ((lr & 3) << 1) | ((lr >> 3) & 1);
  const int swK0 = (quad ^ keyK) * 8, swK1 = ((4 + quad) ^ keyK) * 8;
  const int swV0 = (quad ^ keyV) * 8, swV1 = ((4 + quad) ^ keyV) * 8;
  const int rkbase = ((lr >> 2) & 3) * 8 + (lr & 3);  // sigma row base for this lane
  auto body = [&](const __bf16* KT, const __bf16* VT, const bf16x8 (&qf)[2],
                  f32x4 (&oa)[4], f32x4& lacc, int myq, bool diag, int kt) {
    f32x4 sj[4];
#pragma unroll
    for (int j = 0; j < 4; ++j) {
      const int rK = (j >> 1) * 32 + (j & 1) * 4 + rkbase;
      bf16x8 kf0 = *(const bf16x8*)&KT[rK * 64 + swK0];
      bf16x8 kf1 = *(const bf16x8*)&KT[rK * 64 + swK1];
      f32x4 z = {};
      z = __builtin_amdgcn_mfma_f32_16x16x32_bf16(kf0, qf[0], z, 0, 0, 0);
      z = __builtin_amdgcn_mfma_f32_16x16x32_bf16(kf1, qf[1], z, 0, 0, 0);
      sj[j] = z;
    }
    if (diag) {
#pragma unroll
      for (int j = 0; j < 4; ++j)
#pragma unroll
        for (int r = 0; r < 4; ++r) {
          int key = kt * 64 + (j >> 1) * 32 + quad * 8 + (j & 1) * 4 + r;
          if (key > myq) sj[j][r] = -3.0e38f;  // exp2 -> 0
        }
    }
    bf16x8 pf0, pf1;
#pragma unroll
    for (int j = 0; j < 4; ++j)
#pragma unroll
      for (int r = 0; r < 4; ++r) {
        float pv = exp2f(sj[j][r]);
        const int jj = (j & 1) * 4 + r;
        if (j < 2) pf0[jj] = (__bf16)pv; else pf1[jj] = (__bf16)pv;
      }
#pragma unroll
    for (int dt = 0; dt < 4; ++dt) {
      bf16x8 vf0 = *(const bf16x8*)&VT[(dt * 16 + lr) * 64 + swV0];
      bf16x8 vf1 = *(const bf16x8*)&VT[(dt * 16 + lr) * 64 + swV1];
      oa[dt] = __builtin_amdgcn_mfma_f32_16x16x32_bf16(pf0, vf0, oa[dt], 0, 0, 0);
      oa[dt] = __builtin_amdgcn_mfma_f32_16x16x32_bf16(pf1, vf1, oa[dt], 0, 0, 0);
    }
    lacc = __builtin_amdgcn_mfma_f32_16x16x32_bf16(pf0, vones, lacc, 0, 0, 0);
    lacc = __builtin_amdgcn_mfma_f32_16x16x32_bf16(pf1, vones, lacc, 0, 0, 0);
  };
  // prologue
  stage(0, K0s, V0s);
  __syncthreads();  // drains DMA -> tile 0 ready
  int kt = 0;
  while (true) {
    if (kt < qhi) stage(kt + 1, K1s, V1s);
    if (kt <= qlo) body(K0s, V0s, qfl, oaL, lL, qrow_lo + lr, kt == qlo, kt);
    body(K0s, V0s, qfh, oaH, lH, qrow_hi + lr, kt == qhi, kt);
    __syncthreads();  // drains kt+1 DMA; guards buf0 reuse
    ++kt;
    if (kt > qhi) break;
    if (kt < qhi) stage(kt + 1, K0s, V0s);
    if (kt <= qlo) body(K1s, V1s, qfl, oaL, lL, qrow_lo + lr, kt == qlo, kt);
    body(K1s, V1s, qfh, oaH, lH, qrow_hi + lr, kt == qhi, kt);
    __syncthreads();
    ++kt;
    if (kt > qhi) break;
  }
  // epilogue: lacc[r] is already l of q-row quad*4+r -> direct divide, no shfl
#pragma unroll
  for (int r = 0; r < 4; ++r) {
    float ilL = 1.0f / lL[r];
    float ilH = 1.0f / lH[r];
#pragma unroll
    for (int dt = 0; dt < 4; ++dt) {
      size_t rowL = (size_t)b * T_DIM + qrow_lo + quad * 4 + r;
      size_t rowH = (size_t)b * T_DIM + qrow_hi + quad * 4 + r;
      o[rowL * C_DIM + h * HD_DIM + dt * 16 + lr] = (__bf16)(oaL[dt][r] * ilL);
      o[rowH * C_DIM + h * HD_DIM + dt * 16 + lr] = (__bf16)(oaH[dt][r] * ilH);
    }
  }
}

extern "C" void kernel_launch(void* const* d_in, const int* in_sizes, int n_in,
                              void* d_out, int out_size, void* d_ws, size_t ws_size,
                              hipStream_t stream) {
  const float* x    = (const float*)d_in[0];  // [B,T,C]
  const float* wqkv = (const float*)d_in[1];  // [3C,C]
  const float* wout = (const float*)d_in[2];  // [C,C]
  const float* cosp = (const float*)d_in[3];  // [1,1,512,8]
  const float* sinp = (const float*)d_in[4];  // [1,1,512,8]
  float* out = (float*)d_out;

  char* ws = (char*)d_ws;
  __bf16* xb    = (__bf16*)(ws);                    // 50331648 B
  __bf16* qb    = (__bf16*)(ws + 50331648);         // 50331648 B [M][384]
  __bf16* kb    = (__bf16*)(ws + 100663296);        // 50331648 B [M][384]
  __bf16* vtb   = (__bf16*)(ws + 150994944);        // 50331648 B [b*6+h][64][512]
  __bf16* ob    = (__bf16*)(ws + 201326592);        // 50331648 B [M][384]
  __bf16* wqkvb = (__bf16*)(ws + 251658240);        // 884736 B
  __bf16* woutb = (__bf16*)(ws + 252542976);        // 294912 B
  // total ws use: 252837888 bytes (identical to all prior clean runs)

  const int M = B_DIM * T_DIM;  // 65536

  // fused casts: 6291456 + 110592 + 36864 = 6438912 float4 units = 25152 blocks
  cast_all<<<25152, 256, 0, stream>>>(x, wqkv, wout, xb, wqkvb, woutb);

  // qkv = x @ Wqkv^T, epilogue splits: q (scaled+rope) / k (rope) / v^T -> vt
  gemm_bt<<<dim3(QKV_LD / 128, M / 128), 256, 0, stream>>>(
      xb, wqkvb, qb, kb, vtb, (float*)nullptr, cosp, sinp, M, QKV_LD, C_DIM);

  // causal flash attention -> o [65536][384] bf16 (1-D grid, T1 XCD swizzle)
  attn_kernel<<<3072, 256, 0, stream>>>(qb, kb, vtb, ob);

  // out = o @ Wout^T : fp32 (T1 swizzle, generic path)
  gemm_bt<<<dim3(C_DIM / 128, M / 128), 256, 0, stream>>>(
      ob, woutb, (__bf16*)nullptr, (__bf16*)nullptr, (__bf16*)nullptr, out,
      (const float*)nullptr, (const float*)nullptr, M, C_DIM, C_DIM);
}